// Round 1
// baseline (740.885 us; speedup 1.0000x reference)
//
#include <hip/hip_runtime.h>
#include <math.h>

// Problem constants (fixed shapes from reference)
#define B_  4
#define CK_ 64
#define N_  4032   // memory axis (softmax axis), T*H*W with T=1
#define M_  4032   // query axis, H*W
#define MT  4      // m-columns per block

// One block handles MT columns (all N rows) for one batch.
// LDS: aff[MT][N] = 64512 B  (+ small qk tile / reduction scratch)
__global__ __launch_bounds__(256, 2) void attn_mem_kernel(
    const float* __restrict__ mk,   // [B, CK, 1, H, W] -> [B, CK, N]
    const float* __restrict__ qk,   // [B, CK, H, W]    -> [B, CK, M]
    float* __restrict__ out)        // [B, N, M]
{
    __shared__ float aff[MT * N_];     // logits, then exp() values
    __shared__ float qs[CK_ * MT];     // qk column tile, [c][j]
    __shared__ float cc[MT];           // sum_c qk^2 per column
    __shared__ float red[MT];          // column max
    __shared__ float rsum[MT];         // 1/sumexp per column

    const int tid = threadIdx.x;
    const int m0  = blockIdx.x * MT;
    const int b   = blockIdx.y;

    // ---- Phase 0: stage qk columns ----
    {
        const int c = tid >> 2;        // 0..63
        const int j = tid & 3;         // 0..3
        qs[c * MT + j] = qk[((size_t)b * CK_ + c) * M_ + m0 + j];
    }
    __syncthreads();
    if (tid < MT) {
        float s = 0.f;
        for (int c = 0; c < CK_; ++c) { const float v = qs[c * MT + tid]; s = fmaf(v, v, s); }
        cc[tid] = s;
    }
    __syncthreads();

    const float cc0 = cc[0], cc1 = cc[1], cc2 = cc[2], cc3 = cc[3];

    // ---- Phase 1: affinity GEMM (fp32 FMA), logits -> LDS ----
    const float* mkb = mk + (size_t)b * CK_ * N_;
    for (int chunk = 0; chunk < 4; ++chunk) {
        const int n0 = chunk * 1024 + tid * 4;
        if (n0 < N_) {
            float acc[4][MT];
            float an[4];
            #pragma unroll
            for (int i = 0; i < 4; ++i) {
                an[i] = 0.f;
                #pragma unroll
                for (int j = 0; j < MT; ++j) acc[i][j] = 0.f;
            }
            const float* p = mkb + n0;
            #pragma unroll 4
            for (int c = 0; c < CK_; ++c) {
                const float4 v = *(const float4*)(p + (size_t)c * N_);
                const float q0 = qs[c * MT + 0];
                const float q1 = qs[c * MT + 1];
                const float q2 = qs[c * MT + 2];
                const float q3 = qs[c * MT + 3];
                const float vv[4] = {v.x, v.y, v.z, v.w};
                #pragma unroll
                for (int i = 0; i < 4; ++i) {
                    an[i]     = fmaf(vv[i], vv[i], an[i]);
                    acc[i][0] = fmaf(vv[i], q0, acc[i][0]);
                    acc[i][1] = fmaf(vv[i], q1, acc[i][1]);
                    acc[i][2] = fmaf(vv[i], q2, acc[i][2]);
                    acc[i][3] = fmaf(vv[i], q3, acc[i][3]);
                }
            }
            const float ccv[4] = {cc0, cc1, cc2, cc3};
            #pragma unroll
            for (int j = 0; j < MT; ++j) {
                #pragma unroll
                for (int i = 0; i < 4; ++i) {
                    // (-a + 2*dot - c) / sqrt(CK)
                    aff[j * N_ + n0 + i] = (2.f * acc[i][j] - an[i] - ccv[j]) * 0.125f;
                }
            }
        }
    }
    __syncthreads();

    // ---- Phase 2: per-column softmax stats (one wave per column) ----
    const int col  = tid >> 6;   // 0..3
    const int lane = tid & 63;
    {
        float mx = -1e30f;
        for (int n = lane; n < N_; n += 64) mx = fmaxf(mx, aff[col * N_ + n]);
        #pragma unroll
        for (int off = 32; off > 0; off >>= 1) mx = fmaxf(mx, __shfl_down(mx, off));
        if (lane == 0) red[col] = mx;
    }
    __syncthreads();
    {
        const float maxv = red[col];
        float s = 0.f;
        for (int n = lane; n < N_; n += 64) {
            const float e = __expf(aff[col * N_ + n] - maxv);
            aff[col * N_ + n] = e;
            s += e;
        }
        #pragma unroll
        for (int off = 32; off > 0; off >>= 1) s += __shfl_down(s, off);
        if (lane == 0) rsum[col] = 1.f / s;
    }
    __syncthreads();

    // ---- Phase 3: normalize + store (float4 per row of 4 columns) ----
    const float r0 = rsum[0], r1 = rsum[1], r2 = rsum[2], r3 = rsum[3];
    float* ob = out + ((size_t)b * N_) * M_ + m0;
    for (int n = tid; n < N_; n += 256) {
        float4 o;
        o.x = aff[0 * N_ + n] * r0;
        o.y = aff[1 * N_ + n] * r1;
        o.z = aff[2 * N_ + n] * r2;
        o.w = aff[3 * N_ + n] * r3;
        *(float4*)(ob + (size_t)n * M_) = o;
    }
}

extern "C" void kernel_launch(void* const* d_in, const int* in_sizes, int n_in,
                              void* d_out, int out_size, void* d_ws, size_t ws_size,
                              hipStream_t stream) {
    const float* mk = (const float*)d_in[0];
    const float* qk = (const float*)d_in[1];
    float* out = (float*)d_out;

    dim3 grid(M_ / MT, B_);   // 1008 x 4
    dim3 block(256);
    attn_mem_kernel<<<grid, block, 0, stream>>>(mk, qk, out);
}

// Round 2
// 605.320 us; speedup vs baseline: 1.2240x; 1.2240x over previous
//
#include <hip/hip_runtime.h>
#include <math.h>

// Problem constants (fixed shapes from reference)
#define B_  4
#define CK_ 64
#define N_  4032   // memory axis (softmax axis)
#define M_  4032   // query axis
#define MT1 16     // columns per block in pass 1

// ---------------- Pass 1: column softmax denominators -----------------------
// For each (b, m): rcol = 1 / sum_n exp(aff(n,m)).  No max-subtraction:
// aff = -||mk-qk||^2/8 <= 0, exp() in [e^-60, 1] for this data -> safe fp32.
// Side outputs: an_ws[b][n] = sum_c mk^2 (written by blockIdx.x==0 only),
//               cm_ws[b][m] = sum_c qk^2.
__global__ __launch_bounds__(256) void pass1_stats(
    const float* __restrict__ mk,   // [B, CK, N]
    const float* __restrict__ qk,   // [B, CK, M]
    float* __restrict__ rcol,       // [B*M]
    float* __restrict__ an_ws,      // [B*N]
    float* __restrict__ cm_ws)      // [B*M]
{
    __shared__ float qs[CK_][MT1];   // 4 KB qk column tile
    __shared__ float spart[4][MT1];  // per-wave partial sums

    const int tid = threadIdx.x;
    const int m0  = blockIdx.x * MT1;
    const int b   = blockIdx.y;
    const float* qkb = qk + (size_t)b * CK_ * M_;
    const float* mkb = mk + (size_t)b * CK_ * N_;

    // stage qk tile
    for (int i = tid; i < CK_ * MT1; i += 256) {
        const int c = i >> 4, j = i & 15;
        qs[c][j] = qkb[(size_t)c * M_ + m0 + j];
    }
    __syncthreads();

    __shared__ float cmv[MT1];
    if (tid < MT1) {
        float s = 0.f;
        for (int c = 0; c < CK_; ++c) { const float v = qs[c][tid]; s = fmaf(v, v, s); }
        cmv[tid] = s;
        cm_ws[b * M_ + m0 + tid] = s;
    }
    __syncthreads();

    float s[MT1];
    #pragma unroll
    for (int j = 0; j < MT1; ++j) s[j] = 0.f;

    for (int chunk = 0; chunk < 4; ++chunk) {
        const int n0 = chunk * 1024 + tid * 4;
        if (n0 >= N_) break;   // only chunk 3, tid >= 240

        float acc[4][MT1];
        float an[4] = {0.f, 0.f, 0.f, 0.f};
        #pragma unroll
        for (int i = 0; i < 4; ++i)
            #pragma unroll
            for (int j = 0; j < MT1; ++j) acc[i][j] = 0.f;

        const float* p = mkb + n0;
        #pragma unroll 4
        for (int c = 0; c < CK_; ++c) {
            const float4 v  = *(const float4*)(p + (size_t)c * N_);
            const float4 q0 = *(const float4*)&qs[c][0];
            const float4 q1 = *(const float4*)&qs[c][4];
            const float4 q2 = *(const float4*)&qs[c][8];
            const float4 q3 = *(const float4*)&qs[c][12];
            const float vv[4] = {v.x, v.y, v.z, v.w};
            #pragma unroll
            for (int i = 0; i < 4; ++i) {
                const float x = vv[i];
                an[i] = fmaf(x, x, an[i]);
                acc[i][0]  = fmaf(x, q0.x, acc[i][0]);
                acc[i][1]  = fmaf(x, q0.y, acc[i][1]);
                acc[i][2]  = fmaf(x, q0.z, acc[i][2]);
                acc[i][3]  = fmaf(x, q0.w, acc[i][3]);
                acc[i][4]  = fmaf(x, q1.x, acc[i][4]);
                acc[i][5]  = fmaf(x, q1.y, acc[i][5]);
                acc[i][6]  = fmaf(x, q1.z, acc[i][6]);
                acc[i][7]  = fmaf(x, q1.w, acc[i][7]);
                acc[i][8]  = fmaf(x, q2.x, acc[i][8]);
                acc[i][9]  = fmaf(x, q2.y, acc[i][9]);
                acc[i][10] = fmaf(x, q2.z, acc[i][10]);
                acc[i][11] = fmaf(x, q2.w, acc[i][11]);
                acc[i][12] = fmaf(x, q3.x, acc[i][12]);
                acc[i][13] = fmaf(x, q3.y, acc[i][13]);
                acc[i][14] = fmaf(x, q3.z, acc[i][14]);
                acc[i][15] = fmaf(x, q3.w, acc[i][15]);
            }
        }

        #pragma unroll
        for (int i = 0; i < 4; ++i)
            #pragma unroll
            for (int j = 0; j < MT1; ++j)
                s[j] += __expf((2.f * acc[i][j] - an[i] - cmv[j]) * 0.125f);

        if (blockIdx.x == 0) {
            float4 av; av.x = an[0]; av.y = an[1]; av.z = an[2]; av.w = an[3];
            *(float4*)(an_ws + b * N_ + n0) = av;
        }
    }

    // wave butterfly then cross-wave reduce
    #pragma unroll
    for (int j = 0; j < MT1; ++j) {
        float v = s[j];
        #pragma unroll
        for (int off = 32; off > 0; off >>= 1) v += __shfl_down(v, off);
        s[j] = v;
    }
    if ((tid & 63) == 0) {
        #pragma unroll
        for (int j = 0; j < MT1; ++j) spart[tid >> 6][j] = s[j];
    }
    __syncthreads();
    if (tid < MT1) {
        const float tot = spart[0][tid] + spart[1][tid] + spart[2][tid] + spart[3][tid];
        rcol[b * M_ + m0 + tid] = 1.f / tot;
    }
}

// ---------------- Pass 2: recompute + normalized coalesced write ------------
// 64x64 tile per block; thread tile 4n x 4m (float4 along m).
__global__ __launch_bounds__(256) void pass2_write(
    const float* __restrict__ mk, const float* __restrict__ qk,
    const float* __restrict__ rcol, const float* __restrict__ an_ws,
    const float* __restrict__ cm_ws, float* __restrict__ out)
{
    const int tid = threadIdx.x;
    const int tx  = tid & 15;        // m-group
    const int ty  = tid >> 4;        // n-group
    const int m   = blockIdx.x * 64 + tx * 4;
    const int n   = blockIdx.y * 64 + ty * 4;
    const int b   = blockIdx.z;

    const float* mkb = mk + (size_t)b * CK_ * N_ + n;
    const float* qkb = qk + (size_t)b * CK_ * M_ + m;

    float acc[4][4];
    #pragma unroll
    for (int i = 0; i < 4; ++i)
        #pragma unroll
        for (int j = 0; j < 4; ++j) acc[i][j] = 0.f;

    #pragma unroll 4
    for (int c = 0; c < CK_; ++c) {
        const float4 a = *(const float4*)(mkb + (size_t)c * N_);
        const float4 q = *(const float4*)(qkb + (size_t)c * M_);
        const float aa[4] = {a.x, a.y, a.z, a.w};
        #pragma unroll
        for (int i = 0; i < 4; ++i) {
            acc[i][0] = fmaf(aa[i], q.x, acc[i][0]);
            acc[i][1] = fmaf(aa[i], q.y, acc[i][1]);
            acc[i][2] = fmaf(aa[i], q.z, acc[i][2]);
            acc[i][3] = fmaf(aa[i], q.w, acc[i][3]);
        }
    }

    const float4 anv = *(const float4*)(an_ws + b * N_ + n);
    const float4 cmv = *(const float4*)(cm_ws + b * M_ + m);
    const float4 rc  = *(const float4*)(rcol  + b * M_ + m);
    const float an_[4] = {anv.x, anv.y, anv.z, anv.w};

    float* ob = out + ((size_t)b * N_ + n) * M_ + m;
    #pragma unroll
    for (int i = 0; i < 4; ++i) {
        float4 o;
        o.x = __expf((2.f * acc[i][0] - an_[i] - cmv.x) * 0.125f) * rc.x;
        o.y = __expf((2.f * acc[i][1] - an_[i] - cmv.y) * 0.125f) * rc.y;
        o.z = __expf((2.f * acc[i][2] - an_[i] - cmv.z) * 0.125f) * rc.z;
        o.w = __expf((2.f * acc[i][3] - an_[i] - cmv.w) * 0.125f) * rc.w;
        *(float4*)(ob + (size_t)i * M_) = o;
    }
}

extern "C" void kernel_launch(void* const* d_in, const int* in_sizes, int n_in,
                              void* d_out, int out_size, void* d_ws, size_t ws_size,
                              hipStream_t stream) {
    const float* mk = (const float*)d_in[0];
    const float* qk = (const float*)d_in[1];
    float* out = (float*)d_out;

    // workspace layout (floats): rcol[B*M] | an_ws[B*N] | cm_ws[B*M]
    float* rcol  = (float*)d_ws;
    float* an_ws = rcol + B_ * M_;
    float* cm_ws = an_ws + B_ * N_;

    dim3 g1(M_ / MT1, B_);                 // 252 x 4
    pass1_stats<<<g1, 256, 0, stream>>>(mk, qk, rcol, an_ws, cm_ws);

    dim3 g2(M_ / 64, N_ / 64, B_);         // 63 x 63 x 4
    pass2_write<<<g2, 256, 0, stream>>>(mk, qk, rcol, an_ws, cm_ws, out);
}

// Round 3
// 447.177 us; speedup vs baseline: 1.6568x; 1.3536x over previous
//
#include <hip/hip_runtime.h>
#include <math.h>

#define B_  4
#define CK_ 64
#define N_  4032   // memory axis (softmax axis)
#define M_  4032   // query axis

typedef __attribute__((ext_vector_type(8))) short short8;   // 8 bf16 = 4 VGPRs (MFMA A/B frag)
typedef __attribute__((ext_vector_type(4))) float float4v;  // MFMA C/D frag

// fp32 -> bf16 bits, round-to-nearest-even (inputs are finite normals)
__device__ inline unsigned short f2bf(float x) {
    unsigned u = __float_as_uint(x);
    u += 0x7FFF + ((u >> 16) & 1);
    return (unsigned short)(u >> 16);
}
__device__ inline float bf2f(unsigned short h) {
    return __uint_as_float(((unsigned)h) << 16);
}

// ---------------- Prep: transpose to [n][64] bf16 hi/lo + u_n --------------
// in [B][64][N] fp32 -> dst_hi/dst_lo [B][N][64] bf16; for mk also
// u[b][n] = exp(-0.125 * sum_c mk^2)  (softmax col-constant qk^2 term dropped).
__global__ __launch_bounds__(256) void prep_kernel(
    const float* __restrict__ mk, const float* __restrict__ qk,
    unsigned short* __restrict__ mk_hi, unsigned short* __restrict__ mk_lo,
    unsigned short* __restrict__ qk_hi, unsigned short* __restrict__ qk_lo,
    float* __restrict__ u)
{
    __shared__ float tile[64][65];
    __shared__ float sred[4][64];
    const int t  = threadIdx.x;
    const int n0 = blockIdx.x * 64;
    const int b  = blockIdx.y;
    const int which = blockIdx.z;

    const float* src = (which == 0 ? mk : qk) + (size_t)b * CK_ * N_;
    unsigned short* dhi = (which == 0 ? mk_hi : qk_hi) + (size_t)b * N_ * CK_;
    unsigned short* dlo = (which == 0 ? mk_lo : qk_lo) + (size_t)b * N_ * CK_;

    #pragma unroll
    for (int i = 0; i < 16; ++i) {
        const int idx = t + 256 * i;
        const int c = idx >> 6, n = idx & 63;
        tile[c][n] = src[(size_t)c * N_ + n0 + n];
    }
    __syncthreads();

    const int n = t & 63;
    const int g = t >> 6;          // c-group of 16
    unsigned short hbits[16], lbits[16];
    float ssq = 0.f;
    #pragma unroll
    for (int i = 0; i < 16; ++i) {
        const float x = tile[g * 16 + i][n];
        const unsigned short h = f2bf(x);
        hbits[i] = h;
        lbits[i] = f2bf(x - bf2f(h));
        ssq = fmaf(x, x, ssq);
    }
    {
        union { short8 v; unsigned short s[8]; } p0, p1, q0, q1;
        #pragma unroll
        for (int i = 0; i < 8; ++i) {
            p0.s[i] = hbits[i]; p1.s[i] = hbits[8 + i];
            q0.s[i] = lbits[i]; q1.s[i] = lbits[8 + i];
        }
        const size_t base = (size_t)(n0 + n) * CK_ + g * 16;
        *(short8*)(dhi + base)     = p0.v;
        *(short8*)(dhi + base + 8) = p1.v;
        *(short8*)(dlo + base)     = q0.v;
        *(short8*)(dlo + base + 8) = q1.v;
    }
    sred[g][n] = ssq;
    __syncthreads();
    if (which == 0 && t < 64) {
        const float tot = sred[0][t] + sred[1][t] + sred[2][t] + sred[3][t];
        u[(size_t)b * N_ + n0 + t] = __expf(-0.125f * tot);
    }
}

// MFMA 16x16x32 bf16 layouts (verified m89/m91):
//   A: A[m = lane&15][k = (lane>>4)*8 + j], j in [0,8)  -> 16B contiguous per lane
//   B: B[k = (lane>>4)*8 + j][n = lane&15]              -> same addressing on [m][64] rows
//   C/D: col = lane&15, row = (lane>>4)*4 + reg

// ---------------- Pass 1: softmax denominators --------------------------
// Block: 64 m-cols (all n), 4 waves in 2x2 (wn, wm); register colsums -> rinv.
__global__ __launch_bounds__(256) void pass1_kernel(
    const unsigned short* __restrict__ mk_hi, const unsigned short* __restrict__ mk_lo,
    const unsigned short* __restrict__ qk_hi, const unsigned short* __restrict__ qk_lo,
    const float* __restrict__ u, float* __restrict__ rinv)
{
    __shared__ float cs[2][64];
    const int t = threadIdx.x;
    const int wave = t >> 6, lane = t & 63;
    const int wn = wave & 1, wm = wave >> 1;
    const int lcol = lane & 15;
    const int quad = lane >> 4;
    const int b = blockIdx.y;
    const int m_base = blockIdx.x * 64 + wm * 32;

    const unsigned short* mh = mk_hi + (size_t)b * N_ * CK_;
    const unsigned short* ml = mk_lo + (size_t)b * N_ * CK_;
    const unsigned short* qh = qk_hi + (size_t)b * M_ * CK_;
    const unsigned short* ql = qk_lo + (size_t)b * M_ * CK_;
    const float* ub = u + (size_t)b * N_;

    // hoist B (qk) fragments: cg = 16-col group, kc = k-chunk of 32
    short8 bh[2][2], bl[2][2];
    #pragma unroll
    for (int cg = 0; cg < 2; ++cg) {
        const size_t mrow = (size_t)(m_base + cg * 16 + lcol) * CK_;
        #pragma unroll
        for (int kc = 0; kc < 2; ++kc) {
            const size_t off = mrow + kc * 32 + quad * 8;
            bh[cg][kc] = *(const short8*)(qh + off);
            bl[cg][kc] = *(const short8*)(ql + off);
        }
    }

    float p0 = 0.f, p1 = 0.f;   // per-lane col partials (cg=0,1)

    for (int it = 0; it < 63; ++it) {
        const int n_base = it * 64 + wn * 32;
        short8 ah[2][2], al[2][2];
        #pragma unroll
        for (int rg = 0; rg < 2; ++rg) {
            const size_t nrow = (size_t)(n_base + rg * 16 + lcol) * CK_;
            #pragma unroll
            for (int kc = 0; kc < 2; ++kc) {
                const size_t off = nrow + kc * 32 + quad * 8;
                ah[rg][kc] = *(const short8*)(mh + off);
                al[rg][kc] = *(const short8*)(ml + off);
            }
        }
        float uv[2][4];
        #pragma unroll
        for (int rg = 0; rg < 2; ++rg)
            #pragma unroll
            for (int r = 0; r < 4; ++r)
                uv[rg][r] = ub[n_base + rg * 16 + quad * 4 + r];

        #pragma unroll
        for (int rg = 0; rg < 2; ++rg) {
            #pragma unroll
            for (int cg = 0; cg < 2; ++cg) {
                float4v a1 = {0.f, 0.f, 0.f, 0.f};
                float4v a2 = {0.f, 0.f, 0.f, 0.f};
                #pragma unroll
                for (int kc = 0; kc < 2; ++kc) {
                    a1 = __builtin_amdgcn_mfma_f32_16x16x32_bf16(ah[rg][kc], bh[cg][kc], a1, 0, 0, 0);
                    a2 = __builtin_amdgcn_mfma_f32_16x16x32_bf16(ah[rg][kc], bl[cg][kc], a2, 0, 0, 0);
                    a2 = __builtin_amdgcn_mfma_f32_16x16x32_bf16(al[rg][kc], bh[cg][kc], a2, 0, 0, 0);
                }
                float ps = 0.f;
                #pragma unroll
                for (int r = 0; r < 4; ++r) {
                    const float dot = a1[r] + a2[r];
                    ps += uv[rg][r] * __expf(0.25f * dot);
                }
                if (cg == 0) p0 += ps; else p1 += ps;
            }
        }
    }

    // reduce across the 4 quads (rows) -> every lane holds its col total
    p0 += __shfl_xor(p0, 16); p0 += __shfl_xor(p0, 32);
    p1 += __shfl_xor(p1, 16); p1 += __shfl_xor(p1, 32);
    if (lane < 16) {
        cs[wn][wm * 32 + lcol]      = p0;
        cs[wn][wm * 32 + 16 + lcol] = p1;
    }
    __syncthreads();
    if (t < 64) {
        const float tot = cs[0][t] + cs[1][t];
        rinv[(size_t)b * M_ + blockIdx.x * 64 + t] = 1.f / tot;
    }
}

// ---------------- Pass 2: recompute + normalized write ----------------------
// 64x64 tile per block, 4 waves in 2x2, each wave a 32x32 tile (2x2 of 16x16).
__global__ __launch_bounds__(256) void pass2_kernel(
    const unsigned short* __restrict__ mk_hi, const unsigned short* __restrict__ mk_lo,
    const unsigned short* __restrict__ qk_hi, const unsigned short* __restrict__ qk_lo,
    const float* __restrict__ u, const float* __restrict__ rinv,
    float* __restrict__ out)
{
    const int t = threadIdx.x;
    const int wave = t >> 6, lane = t & 63;
    const int wn = wave & 1, wm = wave >> 1;
    const int lcol = lane & 15;
    const int quad = lane >> 4;
    const int b = blockIdx.z;
    const int m_base = blockIdx.x * 64 + wm * 32;
    const int n_base = blockIdx.y * 64 + wn * 32;

    const unsigned short* mh = mk_hi + (size_t)b * N_ * CK_;
    const unsigned short* ml = mk_lo + (size_t)b * N_ * CK_;
    const unsigned short* qh = qk_hi + (size_t)b * M_ * CK_;
    const unsigned short* ql = qk_lo + (size_t)b * M_ * CK_;

    short8 bh[2][2], bl[2][2], ah[2][2], al[2][2];
    #pragma unroll
    for (int cg = 0; cg < 2; ++cg) {
        const size_t mrow = (size_t)(m_base + cg * 16 + lcol) * CK_;
        #pragma unroll
        for (int kc = 0; kc < 2; ++kc) {
            const size_t off = mrow + kc * 32 + quad * 8;
            bh[cg][kc] = *(const short8*)(qh + off);
            bl[cg][kc] = *(const short8*)(ql + off);
        }
    }
    #pragma unroll
    for (int rg = 0; rg < 2; ++rg) {
        const size_t nrow = (size_t)(n_base + rg * 16 + lcol) * CK_;
        #pragma unroll
        for (int kc = 0; kc < 2; ++kc) {
            const size_t off = nrow + kc * 32 + quad * 8;
            ah[rg][kc] = *(const short8*)(mh + off);
            al[rg][kc] = *(const short8*)(ml + off);
        }
    }

    float uv[2][4];
    #pragma unroll
    for (int rg = 0; rg < 2; ++rg)
        #pragma unroll
        for (int r = 0; r < 4; ++r)
            uv[rg][r] = u[(size_t)b * N_ + n_base + rg * 16 + quad * 4 + r];
    float rc[2];
    #pragma unroll
    for (int cg = 0; cg < 2; ++cg)
        rc[cg] = rinv[(size_t)b * M_ + m_base + cg * 16 + lcol];

    float* orow = out + ((size_t)b * N_ + n_base + quad * 4) * M_ + m_base + lcol;

    #pragma unroll
    for (int rg = 0; rg < 2; ++rg) {
        #pragma unroll
        for (int cg = 0; cg < 2; ++cg) {
            float4v a1 = {0.f, 0.f, 0.f, 0.f};
            float4v a2 = {0.f, 0.f, 0.f, 0.f};
            #pragma unroll
            for (int kc = 0; kc < 2; ++kc) {
                a1 = __builtin_amdgcn_mfma_f32_16x16x32_bf16(ah[rg][kc], bh[cg][kc], a1, 0, 0, 0);
                a2 = __builtin_amdgcn_mfma_f32_16x16x32_bf16(ah[rg][kc], bl[cg][kc], a2, 0, 0, 0);
                a2 = __builtin_amdgcn_mfma_f32_16x16x32_bf16(al[rg][kc], bh[cg][kc], a2, 0, 0, 0);
            }
            #pragma unroll
            for (int r = 0; r < 4; ++r) {
                const float dot = a1[r] + a2[r];
                const float val = uv[rg][r] * __expf(0.25f * dot) * rc[cg];
                orow[(size_t)(rg * 16 + r) * M_ + cg * 16] = val;
            }
        }
    }
}

extern "C" void kernel_launch(void* const* d_in, const int* in_sizes, int n_in,
                              void* d_out, int out_size, void* d_ws, size_t ws_size,
                              hipStream_t stream) {
    const float* mk = (const float*)d_in[0];
    const float* qk = (const float*)d_in[1];
    float* out = (float*)d_out;

    // ws layout: mk_hi | mk_lo | qk_hi | qk_lo (bf16 [B][N][64]) | u | rinv (f32)
    unsigned short* mk_hi = (unsigned short*)d_ws;
    unsigned short* mk_lo = mk_hi + (size_t)B_ * N_ * CK_;
    unsigned short* qk_hi = mk_lo + (size_t)B_ * N_ * CK_;
    unsigned short* qk_lo = qk_hi + (size_t)B_ * M_ * CK_;
    float* u    = (float*)(qk_lo + (size_t)B_ * M_ * CK_);
    float* rinv = u + (size_t)B_ * N_;

    prep_kernel<<<dim3(N_ / 64, B_, 2), 256, 0, stream>>>(mk, qk, mk_hi, mk_lo, qk_hi, qk_lo, u);
    pass1_kernel<<<dim3(M_ / 64, B_), 256, 0, stream>>>(mk_hi, mk_lo, qk_hi, qk_lo, u, rinv);
    pass2_kernel<<<dim3(M_ / 64, N_ / 64, B_), 256, 0, stream>>>(mk_hi, mk_lo, qk_hi, qk_lo, u, rinv, out);
}